// Round 22
// baseline (31.768 us; speedup 1.0000x reference)
//
#include <hip/hip_runtime.h>
#include <math.h>

// Problem constants: B=16, N=128, h=256, goal_dim=64, obs_dim=128, local=64, skills=16
// R22 = R21 (27.2us) with proj_k split to 512 blocks x 512 threads (8-row
// windows, 2 blocks/CU): halves per-block serial work, overlaps weight-load
// latency across independent blocks. attn_k byte-identical to R21.

typedef float f32x4 __attribute__((ext_vector_type(4)));
typedef short s16x8 __attribute__((ext_vector_type(8)));

// ---- workspace layout (float offsets) ----
#define WOBF_OFF  0        // bf16 [256][256] (row-major, = original Wo layout)
#define QBF_OFF   32768    // bf16 [2048][256] row-major
#define KBF_OFF   294912   // bf16 [2048][256] row-major
#define VTBF_OFF  557056   // bf16 [16][256][128]  (V transposed per batch)

// ---- output layout (float offsets, tuple return order) ----
#define LOGIT_OFF 0        // [16][128][16]
#define MASK_OFF  32768    // [16][128][128]
#define ATTN_OFF  294912   // [16][128][128]
#define OUT_OFF   557056   // [16][128][256]

static __device__ __forceinline__ unsigned short f2bf(float x) {
  unsigned int u = __float_as_uint(x);
  u = (u + 0x7fffu + ((u >> 16) & 1u)) >> 16;   // RNE
  return (unsigned short)u;
}
static __device__ __forceinline__ float bf2f(unsigned short h) {
  return __uint_as_float(((unsigned int)h) << 16);
}

// split 8 consecutive f32 (16B-aligned) into hi/lo bf16 MFMA fragments
static __device__ __forceinline__ void split8(const float* __restrict__ p,
                                              s16x8* hi, s16x8* lo) {
  float4 x0 = *(const float4*)p;
  float4 x1 = *(const float4*)(p + 4);
  float xs[8] = {x0.x, x0.y, x0.z, x0.w, x1.x, x1.y, x1.z, x1.w};
#pragma unroll
  for (int j = 0; j < 8; j++) {
    unsigned short h = f2bf(xs[j]);
    (*hi)[j] = (short)h;
    (*lo)[j] = (short)f2bf(xs[j] - bf2f(h));
  }
}
#define MFMA(a, b, c) __builtin_amdgcn_mfma_f32_16x16x32_bf16((a), (b), (c), 0, 0, 0)

// ---------------- proj_k: 512 blocks x 512 thr, 8-row windows, 2 blocks/CU ---
// bid -> xcd = bid&7, j = bid>>3 (0..63); bb = 2*xcd + (j&1);
// sub = j>>1 (0..31): rw = sub>>1 (8-row window 0..15), col-half = sub&1.
// MFMA A rows 8-15 duplicate 0-7 (ar = lr&7); only lc<2 output rows stored.
__global__ __launch_bounds__(512, 4) void proj_k(
    const float* __restrict__ goals, const float* __restrict__ agents,
    const float* __restrict__ Wq, const float* __restrict__ bq,
    const float* __restrict__ Wk, const float* __restrict__ bk,
    const float* __restrict__ Wv, const float* __restrict__ bv,
    const float* __restrict__ Wo, float* __restrict__ ws) {
  unsigned short* qbf  = (unsigned short*)(ws + QBF_OFF);
  unsigned short* kbf  = (unsigned short*)(ws + KBF_OFF);
  unsigned short* vtbf = (unsigned short*)(ws + VTBF_OFF);
  unsigned short* wobf = (unsigned short*)(ws + WOBF_OFF);

  __shared__ __align__(16) float xg[8 * 68];
  __shared__ __align__(16) float xa[8 * 132];

  int t = threadIdx.x;
  int bid = blockIdx.x;
  int xcd = bid & 7, j = bid >> 3;
  int bb = 2 * xcd + (j & 1);
  int sub = j >> 1;
  int rw = sub >> 1;
  int colbase = (sub & 1) * 128;
  int r0 = bb * 128 + rw * 8;

  xg[(t >> 6) * 68 + (t & 63)] = goals[(size_t)r0 * 64 + t];
  for (int i = t; i < 1024; i += 512) xa[(i >> 7) * 132 + (i & 127)] = agents[(size_t)r0 * 128 + i];
  if (t < 128) {                                 // Wo -> bf16 (128/block x 512)
    int jj = bid * 128 + t;
    wobf[jj] = f2bf(Wo[jj]);
  }
  __syncthreads();

  int w = t >> 6, l = t & 63, lr = l & 15, lc = l >> 4;
  int oc = colbase + w * 16 + lr;
  int ar = lr & 7;                               // A row (dup 8-15 -> 0-7)

  // ---- Q: k=64, hi/lo ----
  {
    f32x4 acc = {0.f, 0.f, 0.f, 0.f};
#pragma unroll
    for (int kk = 0; kk < 2; kk++) {
      s16x8 ahi, alo, bhi, blo;
      split8(&xg[ar * 68 + kk * 32 + lc * 8], &ahi, &alo);
      split8(&Wq[(size_t)oc * 64 + kk * 32 + lc * 8], &bhi, &blo);
      acc = MFMA(ahi, bhi, acc);
      acc = MFMA(alo, bhi, acc);
      acc = MFMA(ahi, blo, acc);
    }
    if (lc < 2) {
      float bqv = bq[oc];
#pragma unroll
      for (int q = 0; q < 4; q++)
        qbf[(size_t)(r0 + 4 * lc + q) * 256 + oc] = f2bf(acc[q] + bqv);
    }
  }
  // ---- K + V fused: A-splits computed once ----
  {
    f32x4 accK = {0.f, 0.f, 0.f, 0.f};
    f32x4 accV = {0.f, 0.f, 0.f, 0.f};
#pragma unroll
    for (int kk = 0; kk < 4; kk++) {
      s16x8 ahi, alo;
      split8(&xa[ar * 132 + kk * 32 + lc * 8], &ahi, &alo);
      s16x8 bhiK, bloK, bhiV, bloV;
      split8(&Wk[(size_t)oc * 128 + kk * 32 + lc * 8], &bhiK, &bloK);
      split8(&Wv[(size_t)oc * 128 + kk * 32 + lc * 8], &bhiV, &bloV);
      accK = MFMA(ahi, bhiK, accK);
      accK = MFMA(alo, bhiK, accK);
      accK = MFMA(ahi, bloK, accK);
      accV = MFMA(ahi, bhiV, accV);
      accV = MFMA(alo, bhiV, accV);
      accV = MFMA(ahi, bloV, accV);
    }
    if (lc < 2) {
      float bkv = bk[oc], bvv = bv[oc];
      int m0 = rw * 8;
#pragma unroll
      for (int q = 0; q < 4; q++) {
        int rloc = 4 * lc + q;
        kbf[(size_t)(r0 + rloc) * 256 + oc] = f2bf(accK[q] + bkv);
        vtbf[(size_t)(bb * 256 + oc) * 128 + m0 + rloc] = f2bf(accV[q] + bvv);
      }
    }
  }
}

// ---------------- attn_k: byte-identical to R21 ----------------
__global__ __launch_bounds__(1024) void attn_k(
    const float* __restrict__ goals, const float* __restrict__ agents_local,
    const float* __restrict__ u1, const float* __restrict__ u2,
    const float* __restrict__ bo, const float* __restrict__ Wsm,
    const float* __restrict__ bs, const float* __restrict__ ws,
    float* __restrict__ out) {
  const unsigned short* Qbf  = (const unsigned short*)(ws + QBF_OFF);
  const unsigned short* Kbf  = (const unsigned short*)(ws + KBF_OFF);
  const unsigned short* VTbf = (const unsigned short*)(ws + VTBF_OFF);
  const unsigned short* Wobf = (const unsigned short*)(ws + WOBF_OFF);
  float* o_logit = out + LOGIT_OFF;
  float* o_mask  = out + MASK_OFF;
  float* o_attn  = out + ATTN_OFF;
  float* o_out   = out + OUT_OFF;

  int bid = blockIdx.x;
  int xcd = bid & 7, idx = bid >> 3;
  int b  = 2 * xcd + (idx & 1);
  int n0 = (idx >> 1) << 3;
  int rtile = n0 & 0x70;
  int soff  = n0 & 8;
  int t = threadIdx.x;
  int w = t >> 6, l = t & 63, lr = l & 15, lc = l >> 4;

  __shared__ __align__(16) float Spp[2][8][132];
  __shared__ __align__(16) unsigned short Wb[16 * 136];
  __shared__ __align__(16) unsigned short Ib[16 * 264];
  __shared__ __align__(16) float outb[8 * 260];
  __shared__ __align__(16) float Wsb[16 * 384];   // Wsm staged (24 KB)
  __shared__ __align__(16) float cgb[8 * 128];    // agents_local||goals rows (4 KB)

  // ---- SK-input staging (issued FIRST: latency hides under phases L..O) ----
#pragma unroll
  for (int i = 0; i < 6; i++) Wsb[t + i * 1024] = Wsm[t + i * 1024];
  {
    int r = t >> 7, c = t & 127;
    int row = b * 128 + n0 + r;
    cgb[r * 128 + c] = (c < 64) ? agents_local[(size_t)row * 64 + c]
                                : goals[(size_t)row * 64 + (c - 64)];
  }

  // ---- prefetch: u1/u2 (float2, waves 0-7), bo, bs, VT + Wobf frags ----
  float2 uu1v = make_float2(0.f, 0.f), uu2v = make_float2(0.f, 0.f);
  if (w < 8) {
    int srow = b * 128 + n0 + w;
    uu1v = *(const float2*)&u1[(size_t)srow * 128 + 2 * l];
    uu2v = *(const float2*)&u2[(size_t)srow * 128 + 2 * l];
  }
  int h0g = w * 16;
  float bov = bo[h0g + lr];
  float bsv = bs[(t >> 3) & 15];
  const s16x8* vtp = (const s16x8*)(VTbf + (size_t)(b * 256 + h0g + lr) * 128);
  s16x8 fv0 = vtp[lc], fv1 = vtp[4 + lc], fv2 = vtp[8 + lc], fv3 = vtp[12 + lc];
  const s16x8* wop = (const s16x8*)(Wobf + (size_t)(h0g + lr) * 256);
  s16x8 fo0 = wop[lc],      fo1 = wop[4 + lc],  fo2 = wop[8 + lc],  fo3 = wop[12 + lc];
  s16x8 fo4 = wop[16 + lc], fo5 = wop[20 + lc], fo6 = wop[24 + lc], fo7 = wop[28 + lc];

  // ---- phase L: logits MFMA. wave w: m-tile = w&7, k-half = w>>3 ----
  {
    int mt = w & 7, kh = w >> 3;
    const s16x8* ap = (const s16x8*)(Qbf + (size_t)(b * 128 + rtile + lr) * 256 + kh * 128);
    const s16x8* bp = (const s16x8*)(Kbf + (size_t)(b * 128 + mt * 16 + lr) * 256 + kh * 128);
    f32x4 acc = {0.f, 0.f, 0.f, 0.f};
#pragma unroll
    for (int kk = 0; kk < 4; kk++)
      acc = MFMA(ap[kk * 4 + lc], bp[kk * 4 + lc], acc);
    if ((lc >> 1) == (soff >> 3)) {
#pragma unroll
      for (int q = 0; q < 4; q++) Spp[kh][(4 * lc + q) & 7][mt * 16 + lr] = acc[q];
    }
    if (t < 544) ((unsigned int*)(Wb + (soff ^ 8) * 136))[t] = 0u;
  }
  __syncthreads();

  // ---- phase S: softmax, one row per wave (waves 0-7), pure shfl, 0 barriers -
  if (w < 8) {
    int m0 = 2 * l;
    int row = b * 128 + n0 + w;
    float lg0 = (Spp[0][w][m0]     + Spp[1][w][m0])     * 0.0625f;
    float lg1 = (Spp[0][w][m0 + 1] + Spp[1][w][m0 + 1]) * 0.0625f;
    float g10 = -__logf(-__logf(uu1v.x + 1e-20f) + 1e-20f);
    float g20 = -__logf(-__logf(uu2v.x + 1e-20f) + 1e-20f);
    float g11 = -__logf(-__logf(uu1v.y + 1e-20f) + 1e-20f);
    float g21 = -__logf(-__logf(uu2v.y + 1e-20f) + 1e-20f);
    float mk0 = 1.0f / (1.0f + __expf(-(lg0 + g10 - g20)));   // TAU = 1
    float mk1 = 1.0f / (1.0f + __expf(-(lg1 + g11 - g21)));
    *(float2*)&o_mask[(size_t)row * 128 + m0] = make_float2(mk0, mk1);
    float sc0 = lg0 + __logf(mk0 + 1e-8f);
    float sc1 = lg1 + __logf(mk1 + 1e-8f);
    float v = fmaxf(sc0, sc1);
#pragma unroll
    for (int off = 32; off >= 1; off >>= 1) v = fmaxf(v, __shfl_xor(v, off));
    float e0 = __expf(sc0 - v), e1 = __expf(sc1 - v);
    float s = e0 + e1;
#pragma unroll
    for (int off = 32; off >= 1; off >>= 1) s += __shfl_xor(s, off);
    float at0 = e0 / s, at1 = e1 / s;
    *(float2*)&o_attn[(size_t)row * 128 + m0] = make_float2(at0, at1);
    Wb[(soff + w) * 136 + m0]     = f2bf(at0 * mk0);
    Wb[(soff + w) * 136 + m0 + 1] = f2bf(at1 * mk1);
  }
  __syncthreads();

  // ---- phase PV: info = W x V. wave w -> h-tile h0g (4 MFMAs, prefetched B) --
  {
    s16x8 a0 = *(const s16x8*)(Wb + lr * 136 + 0 * 32 + lc * 8);
    s16x8 a1 = *(const s16x8*)(Wb + lr * 136 + 1 * 32 + lc * 8);
    s16x8 a2 = *(const s16x8*)(Wb + lr * 136 + 2 * 32 + lc * 8);
    s16x8 a3 = *(const s16x8*)(Wb + lr * 136 + 3 * 32 + lc * 8);
    f32x4 acc = {0.f, 0.f, 0.f, 0.f};
    acc = MFMA(a0, fv0, acc);
    acc = MFMA(a1, fv1, acc);
    acc = MFMA(a2, fv2, acc);
    acc = MFMA(a3, fv3, acc);
#pragma unroll
    for (int q = 0; q < 4; q++) Ib[(4 * lc + q) * 264 + h0g + lr] = f2bf(acc[q]);
  }
  __syncthreads();

  // ---- phase O: out = info x Wo^T. wave w -> g-tile (8 MFMAs, prefetched B) --
  {
    f32x4 acc = {0.f, 0.f, 0.f, 0.f};
    acc = MFMA(*(const s16x8*)(Ib + lr * 264 + 0 * 32 + lc * 8), fo0, acc);
    acc = MFMA(*(const s16x8*)(Ib + lr * 264 + 1 * 32 + lc * 8), fo1, acc);
    acc = MFMA(*(const s16x8*)(Ib + lr * 264 + 2 * 32 + lc * 8), fo2, acc);
    acc = MFMA(*(const s16x8*)(Ib + lr * 264 + 3 * 32 + lc * 8), fo3, acc);
    acc = MFMA(*(const s16x8*)(Ib + lr * 264 + 4 * 32 + lc * 8), fo4, acc);
    acc = MFMA(*(const s16x8*)(Ib + lr * 264 + 5 * 32 + lc * 8), fo5, acc);
    acc = MFMA(*(const s16x8*)(Ib + lr * 264 + 6 * 32 + lc * 8), fo6, acc);
    acc = MFMA(*(const s16x8*)(Ib + lr * 264 + 7 * 32 + lc * 8), fo7, acc);
    if ((lc >> 1) == (soff >> 3)) {
#pragma unroll
      for (int q = 0; q < 4; q++) {
        int rloc = (4 * lc + q) & 7;
        float val = acc[q] + bov;
        __builtin_nontemporal_store(val, &o_out[(size_t)(b * 128 + n0 + rloc) * 256 + h0g + lr]);
        outb[rloc * 260 + h0g + lr] = val;
      }
    }
  }
  __syncthreads();

  // ---- phase K: skill logits, all inputs from LDS. t = (rloc<<7)|(s<<3)|p ---
  {
    int rloc = t >> 7, s = (t >> 3) & 15, p = t & 7;
    int row = b * 128 + n0 + rloc;
    const float* wsr = &Wsb[s * 384];
    float acc = 0.f;
#pragma unroll
    for (int i = 0; i < 12; i++) {
      int cc = p * 48 + i * 4;
      float4 c4;
      if (cc < 128) c4 = *(const float4*)&cgb[rloc * 128 + cc];
      else          c4 = *(const float4*)&outb[rloc * 260 + (cc - 128)];
      float4 w4 = *(const float4*)&wsr[cc];
      acc = fmaf(w4.x, c4.x, fmaf(w4.y, c4.y, fmaf(w4.z, c4.z, fmaf(w4.w, c4.w, acc))));
    }
    acc += __shfl_xor(acc, 1);
    acc += __shfl_xor(acc, 2);
    acc += __shfl_xor(acc, 4);
    if (p == 0) __builtin_nontemporal_store(acc + bsv, &o_logit[row * 16 + s]);
  }
}

extern "C" void kernel_launch(void* const* d_in, const int* in_sizes, int n_in,
                              void* d_out, int out_size, void* d_ws, size_t ws_size,
                              hipStream_t stream) {
  const float* goals        = (const float*)d_in[0];
  const float* agents       = (const float*)d_in[1];
  const float* agents_local = (const float*)d_in[2];
  const float* u1           = (const float*)d_in[3];
  const float* u2           = (const float*)d_in[4];
  const float* Wq = (const float*)d_in[5];
  const float* bq = (const float*)d_in[6];
  const float* Wk = (const float*)d_in[7];
  const float* bk = (const float*)d_in[8];
  const float* Wv = (const float*)d_in[9];
  const float* bv = (const float*)d_in[10];
  const float* Wo = (const float*)d_in[11];
  const float* bo = (const float*)d_in[12];
  const float* Wsm = (const float*)d_in[13];
  const float* bs  = (const float*)d_in[14];
  float* out = (float*)d_out;
  float* ws  = (float*)d_ws;

  proj_k<<<512, 512, 0, stream>>>(goals, agents, Wq, bq, Wk, bk, Wv, bv, Wo, ws);
  attn_k<<<256, 1024, 0, stream>>>(goals, agents_local, u1, u2, bo, Wsm, bs, ws, out);
}

// Round 23
// 27.263 us; speedup vs baseline: 1.1652x; 1.1652x over previous
//
#include <hip/hip_runtime.h>
#include <math.h>

// Problem constants: B=16, N=128, h=256, goal_dim=64, obs_dim=128, local=64, skills=16
// FINAL (R23) = R21 verbatim — session optimum, 27.2 us (2.3x over round-1).
// R22's proj split regressed (31.8); reverted.
// Structure: proj_k (256x512, 1 blk/CU, hi/lo bf16 MFMA Q/K/V, XCD-aligned) ->
// attn_k (256x1024, 16 waves, XCD-local, phases L/S/PV/O/SK with all loads
// hoisted before their consuming barrier; barrier-free wave-per-row softmax).

typedef float f32x4 __attribute__((ext_vector_type(4)));
typedef short s16x8 __attribute__((ext_vector_type(8)));

// ---- workspace layout (float offsets) ----
#define WOBF_OFF  0        // bf16 [256][256] (row-major, = original Wo layout)
#define QBF_OFF   32768    // bf16 [2048][256] row-major
#define KBF_OFF   294912   // bf16 [2048][256] row-major
#define VTBF_OFF  557056   // bf16 [16][256][128]  (V transposed per batch)

// ---- output layout (float offsets, tuple return order) ----
#define LOGIT_OFF 0        // [16][128][16]
#define MASK_OFF  32768    // [16][128][128]
#define ATTN_OFF  294912   // [16][128][128]
#define OUT_OFF   557056   // [16][128][256]

static __device__ __forceinline__ unsigned short f2bf(float x) {
  unsigned int u = __float_as_uint(x);
  u = (u + 0x7fffu + ((u >> 16) & 1u)) >> 16;   // RNE
  return (unsigned short)u;
}
static __device__ __forceinline__ float bf2f(unsigned short h) {
  return __uint_as_float(((unsigned int)h) << 16);
}

// split 8 consecutive f32 (16B-aligned) into hi/lo bf16 MFMA fragments
static __device__ __forceinline__ void split8(const float* __restrict__ p,
                                              s16x8* hi, s16x8* lo) {
  float4 x0 = *(const float4*)p;
  float4 x1 = *(const float4*)(p + 4);
  float xs[8] = {x0.x, x0.y, x0.z, x0.w, x1.x, x1.y, x1.z, x1.w};
#pragma unroll
  for (int j = 0; j < 8; j++) {
    unsigned short h = f2bf(xs[j]);
    (*hi)[j] = (short)h;
    (*lo)[j] = (short)f2bf(xs[j] - bf2f(h));
  }
}
#define MFMA(a, b, c) __builtin_amdgcn_mfma_f32_16x16x32_bf16((a), (b), (c), 0, 0, 0)

// ---------------- proj_k: 256 blocks x 512 thr, XCD-aligned ----------------
__global__ __launch_bounds__(512) void proj_k(
    const float* __restrict__ goals, const float* __restrict__ agents,
    const float* __restrict__ Wq, const float* __restrict__ bq,
    const float* __restrict__ Wk, const float* __restrict__ bk,
    const float* __restrict__ Wv, const float* __restrict__ bv,
    const float* __restrict__ Wo, float* __restrict__ ws) {
  unsigned short* qbf  = (unsigned short*)(ws + QBF_OFF);
  unsigned short* kbf  = (unsigned short*)(ws + KBF_OFF);
  unsigned short* vtbf = (unsigned short*)(ws + VTBF_OFF);
  unsigned short* wobf = (unsigned short*)(ws + WOBF_OFF);

  __shared__ __align__(16) float xg[16 * 68];
  __shared__ __align__(16) float xa[16 * 132];

  int t = threadIdx.x;
  int bid = blockIdx.x;
  int xcd = bid & 7, j = bid >> 3;
  int bb = 2 * xcd + (j & 1);
  int sub = j >> 1;
  int r0 = bb * 128 + (sub >> 1) * 16;
  int colbase = (sub & 1) * 128;

  for (int i = t; i < 1024; i += 512) xg[(i >> 6) * 68 + (i & 63)] = goals[(size_t)r0 * 64 + i];
  for (int i = t; i < 2048; i += 512) xa[(i >> 7) * 132 + (i & 127)] = agents[(size_t)r0 * 128 + i];
  if (t < 256) {
    int jj = bid * 256 + t;
    wobf[jj] = f2bf(Wo[jj]);
  }
  __syncthreads();

  int w = t >> 6, l = t & 63, lr = l & 15, lc = l >> 4;
  int oc = colbase + w * 16 + lr;

  // ---- Q: k=64, hi/lo ----
  {
    f32x4 acc = {0.f, 0.f, 0.f, 0.f};
#pragma unroll
    for (int kk = 0; kk < 2; kk++) {
      s16x8 ahi, alo, bhi, blo;
      split8(&xg[lr * 68 + kk * 32 + lc * 8], &ahi, &alo);
      split8(&Wq[(size_t)oc * 64 + kk * 32 + lc * 8], &bhi, &blo);
      acc = MFMA(ahi, bhi, acc);
      acc = MFMA(alo, bhi, acc);
      acc = MFMA(ahi, blo, acc);
    }
    float bqv = bq[oc];
#pragma unroll
    for (int q = 0; q < 4; q++)
      qbf[(size_t)(r0 + 4 * lc + q) * 256 + oc] = f2bf(acc[q] + bqv);
  }
  // ---- K + V fused: A-splits computed once, reused for both ----
  {
    f32x4 accK = {0.f, 0.f, 0.f, 0.f};
    f32x4 accV = {0.f, 0.f, 0.f, 0.f};
#pragma unroll
    for (int kk = 0; kk < 4; kk++) {
      s16x8 ahi, alo;
      split8(&xa[lr * 132 + kk * 32 + lc * 8], &ahi, &alo);
      s16x8 bhiK, bloK, bhiV, bloV;
      split8(&Wk[(size_t)oc * 128 + kk * 32 + lc * 8], &bhiK, &bloK);
      split8(&Wv[(size_t)oc * 128 + kk * 32 + lc * 8], &bhiV, &bloV);
      accK = MFMA(ahi, bhiK, accK);
      accK = MFMA(alo, bhiK, accK);
      accK = MFMA(ahi, bloK, accK);
      accV = MFMA(ahi, bhiV, accV);
      accV = MFMA(alo, bhiV, accV);
      accV = MFMA(ahi, bloV, accV);
    }
    float bkv = bk[oc], bvv = bv[oc];
    int m0 = r0 & 127;
#pragma unroll
    for (int q = 0; q < 4; q++) {
      kbf[(size_t)(r0 + 4 * lc + q) * 256 + oc] = f2bf(accK[q] + bkv);
      vtbf[(size_t)(bb * 256 + oc) * 128 + m0 + 4 * lc + q] = f2bf(accV[q] + bvv);
    }
  }
}

// ---------------- attn_k: 256 blocks x 1024 thr, XCD-local ----------------
__global__ __launch_bounds__(1024) void attn_k(
    const float* __restrict__ goals, const float* __restrict__ agents_local,
    const float* __restrict__ u1, const float* __restrict__ u2,
    const float* __restrict__ bo, const float* __restrict__ Wsm,
    const float* __restrict__ bs, const float* __restrict__ ws,
    float* __restrict__ out) {
  const unsigned short* Qbf  = (const unsigned short*)(ws + QBF_OFF);
  const unsigned short* Kbf  = (const unsigned short*)(ws + KBF_OFF);
  const unsigned short* VTbf = (const unsigned short*)(ws + VTBF_OFF);
  const unsigned short* Wobf = (const unsigned short*)(ws + WOBF_OFF);
  float* o_logit = out + LOGIT_OFF;
  float* o_mask  = out + MASK_OFF;
  float* o_attn  = out + ATTN_OFF;
  float* o_out   = out + OUT_OFF;

  int bid = blockIdx.x;
  int xcd = bid & 7, idx = bid >> 3;
  int b  = 2 * xcd + (idx & 1);
  int n0 = (idx >> 1) << 3;
  int rtile = n0 & 0x70;
  int soff  = n0 & 8;
  int t = threadIdx.x;
  int w = t >> 6, l = t & 63, lr = l & 15, lc = l >> 4;

  __shared__ __align__(16) float Spp[2][8][132];
  __shared__ __align__(16) unsigned short Wb[16 * 136];
  __shared__ __align__(16) unsigned short Ib[16 * 264];
  __shared__ __align__(16) float outb[8 * 260];
  __shared__ __align__(16) float Wsb[16 * 384];   // Wsm staged (24 KB)
  __shared__ __align__(16) float cgb[8 * 128];    // agents_local||goals rows (4 KB)

  // ---- SK-input staging (issued FIRST: latency hides under phases L..O) ----
#pragma unroll
  for (int i = 0; i < 6; i++) Wsb[t + i * 1024] = Wsm[t + i * 1024];
  {
    int r = t >> 7, c = t & 127;
    int row = b * 128 + n0 + r;
    cgb[r * 128 + c] = (c < 64) ? agents_local[(size_t)row * 64 + c]
                                : goals[(size_t)row * 64 + (c - 64)];
  }

  // ---- prefetch: u1/u2 (float2, waves 0-7), bo, bs, VT + Wobf frags ----
  float2 uu1v = make_float2(0.f, 0.f), uu2v = make_float2(0.f, 0.f);
  if (w < 8) {
    int srow = b * 128 + n0 + w;
    uu1v = *(const float2*)&u1[(size_t)srow * 128 + 2 * l];
    uu2v = *(const float2*)&u2[(size_t)srow * 128 + 2 * l];
  }
  int h0g = w * 16;
  float bov = bo[h0g + lr];
  float bsv = bs[(t >> 3) & 15];
  const s16x8* vtp = (const s16x8*)(VTbf + (size_t)(b * 256 + h0g + lr) * 128);
  s16x8 fv0 = vtp[lc], fv1 = vtp[4 + lc], fv2 = vtp[8 + lc], fv3 = vtp[12 + lc];
  const s16x8* wop = (const s16x8*)(Wobf + (size_t)(h0g + lr) * 256);
  s16x8 fo0 = wop[lc],      fo1 = wop[4 + lc],  fo2 = wop[8 + lc],  fo3 = wop[12 + lc];
  s16x8 fo4 = wop[16 + lc], fo5 = wop[20 + lc], fo6 = wop[24 + lc], fo7 = wop[28 + lc];

  // ---- phase L: logits MFMA. wave w: m-tile = w&7, k-half = w>>3 ----
  {
    int mt = w & 7, kh = w >> 3;
    const s16x8* ap = (const s16x8*)(Qbf + (size_t)(b * 128 + rtile + lr) * 256 + kh * 128);
    const s16x8* bp = (const s16x8*)(Kbf + (size_t)(b * 128 + mt * 16 + lr) * 256 + kh * 128);
    f32x4 acc = {0.f, 0.f, 0.f, 0.f};
#pragma unroll
    for (int kk = 0; kk < 4; kk++)
      acc = MFMA(ap[kk * 4 + lc], bp[kk * 4 + lc], acc);
    if ((lc >> 1) == (soff >> 3)) {
#pragma unroll
      for (int q = 0; q < 4; q++) Spp[kh][(4 * lc + q) & 7][mt * 16 + lr] = acc[q];
    }
    if (t < 544) ((unsigned int*)(Wb + (soff ^ 8) * 136))[t] = 0u;
  }
  __syncthreads();

  // ---- phase S: softmax, one row per wave (waves 0-7), pure shfl, 0 barriers -
  if (w < 8) {
    int m0 = 2 * l;
    int row = b * 128 + n0 + w;
    float lg0 = (Spp[0][w][m0]     + Spp[1][w][m0])     * 0.0625f;
    float lg1 = (Spp[0][w][m0 + 1] + Spp[1][w][m0 + 1]) * 0.0625f;
    float g10 = -__logf(-__logf(uu1v.x + 1e-20f) + 1e-20f);
    float g20 = -__logf(-__logf(uu2v.x + 1e-20f) + 1e-20f);
    float g11 = -__logf(-__logf(uu1v.y + 1e-20f) + 1e-20f);
    float g21 = -__logf(-__logf(uu2v.y + 1e-20f) + 1e-20f);
    float mk0 = 1.0f / (1.0f + __expf(-(lg0 + g10 - g20)));   // TAU = 1
    float mk1 = 1.0f / (1.0f + __expf(-(lg1 + g11 - g21)));
    *(float2*)&o_mask[(size_t)row * 128 + m0] = make_float2(mk0, mk1);
    float sc0 = lg0 + __logf(mk0 + 1e-8f);
    float sc1 = lg1 + __logf(mk1 + 1e-8f);
    float v = fmaxf(sc0, sc1);
#pragma unroll
    for (int off = 32; off >= 1; off >>= 1) v = fmaxf(v, __shfl_xor(v, off));
    float e0 = __expf(sc0 - v), e1 = __expf(sc1 - v);
    float s = e0 + e1;
#pragma unroll
    for (int off = 32; off >= 1; off >>= 1) s += __shfl_xor(s, off);
    float at0 = e0 / s, at1 = e1 / s;
    *(float2*)&o_attn[(size_t)row * 128 + m0] = make_float2(at0, at1);
    Wb[(soff + w) * 136 + m0]     = f2bf(at0 * mk0);
    Wb[(soff + w) * 136 + m0 + 1] = f2bf(at1 * mk1);
  }
  __syncthreads();

  // ---- phase PV: info = W x V. wave w -> h-tile h0g (4 MFMAs, prefetched B) --
  {
    s16x8 a0 = *(const s16x8*)(Wb + lr * 136 + 0 * 32 + lc * 8);
    s16x8 a1 = *(const s16x8*)(Wb + lr * 136 + 1 * 32 + lc * 8);
    s16x8 a2 = *(const s16x8*)(Wb + lr * 136 + 2 * 32 + lc * 8);
    s16x8 a3 = *(const s16x8*)(Wb + lr * 136 + 3 * 32 + lc * 8);
    f32x4 acc = {0.f, 0.f, 0.f, 0.f};
    acc = MFMA(a0, fv0, acc);
    acc = MFMA(a1, fv1, acc);
    acc = MFMA(a2, fv2, acc);
    acc = MFMA(a3, fv3, acc);
#pragma unroll
    for (int q = 0; q < 4; q++) Ib[(4 * lc + q) * 264 + h0g + lr] = f2bf(acc[q]);
  }
  __syncthreads();

  // ---- phase O: out = info x Wo^T. wave w -> g-tile (8 MFMAs, prefetched B) --
  {
    f32x4 acc = {0.f, 0.f, 0.f, 0.f};
    acc = MFMA(*(const s16x8*)(Ib + lr * 264 + 0 * 32 + lc * 8), fo0, acc);
    acc = MFMA(*(const s16x8*)(Ib + lr * 264 + 1 * 32 + lc * 8), fo1, acc);
    acc = MFMA(*(const s16x8*)(Ib + lr * 264 + 2 * 32 + lc * 8), fo2, acc);
    acc = MFMA(*(const s16x8*)(Ib + lr * 264 + 3 * 32 + lc * 8), fo3, acc);
    acc = MFMA(*(const s16x8*)(Ib + lr * 264 + 4 * 32 + lc * 8), fo4, acc);
    acc = MFMA(*(const s16x8*)(Ib + lr * 264 + 5 * 32 + lc * 8), fo5, acc);
    acc = MFMA(*(const s16x8*)(Ib + lr * 264 + 6 * 32 + lc * 8), fo6, acc);
    acc = MFMA(*(const s16x8*)(Ib + lr * 264 + 7 * 32 + lc * 8), fo7, acc);
    if ((lc >> 1) == (soff >> 3)) {
#pragma unroll
      for (int q = 0; q < 4; q++) {
        int rloc = (4 * lc + q) & 7;
        float val = acc[q] + bov;
        __builtin_nontemporal_store(val, &o_out[(size_t)(b * 128 + n0 + rloc) * 256 + h0g + lr]);
        outb[rloc * 260 + h0g + lr] = val;
      }
    }
  }
  __syncthreads();

  // ---- phase K: skill logits, all inputs from LDS. t = (rloc<<7)|(s<<3)|p ---
  {
    int rloc = t >> 7, s = (t >> 3) & 15, p = t & 7;
    int row = b * 128 + n0 + rloc;
    const float* wsr = &Wsb[s * 384];
    float acc = 0.f;
#pragma unroll
    for (int i = 0; i < 12; i++) {
      int cc = p * 48 + i * 4;
      float4 c4;
      if (cc < 128) c4 = *(const float4*)&cgb[rloc * 128 + cc];
      else          c4 = *(const float4*)&outb[rloc * 260 + (cc - 128)];
      float4 w4 = *(const float4*)&wsr[cc];
      acc = fmaf(w4.x, c4.x, fmaf(w4.y, c4.y, fmaf(w4.z, c4.z, fmaf(w4.w, c4.w, acc))));
    }
    acc += __shfl_xor(acc, 1);
    acc += __shfl_xor(acc, 2);
    acc += __shfl_xor(acc, 4);
    if (p == 0) __builtin_nontemporal_store(acc + bsv, &o_logit[row * 16 + s]);
  }
}

extern "C" void kernel_launch(void* const* d_in, const int* in_sizes, int n_in,
                              void* d_out, int out_size, void* d_ws, size_t ws_size,
                              hipStream_t stream) {
  const float* goals        = (const float*)d_in[0];
  const float* agents       = (const float*)d_in[1];
  const float* agents_local = (const float*)d_in[2];
  const float* u1           = (const float*)d_in[3];
  const float* u2           = (const float*)d_in[4];
  const float* Wq = (const float*)d_in[5];
  const float* bq = (const float*)d_in[6];
  const float* Wk = (const float*)d_in[7];
  const float* bk = (const float*)d_in[8];
  const float* Wv = (const float*)d_in[9];
  const float* bv = (const float*)d_in[10];
  const float* Wo = (const float*)d_in[11];
  const float* bo = (const float*)d_in[12];
  const float* Wsm = (const float*)d_in[13];
  const float* bs  = (const float*)d_in[14];
  float* out = (float*)d_out;
  float* ws  = (float*)d_ws;

  proj_k<<<256, 512, 0, stream>>>(goals, agents, Wq, bq, Wk, bk, Wv, bv, Wo, ws);
  attn_k<<<256, 1024, 0, stream>>>(goals, agents_local, u1, u2, bo, Wsm, bs, ws, out);
}